// Round 5
// baseline (602.567 us; speedup 1.0000x reference)
//
#include <hip/hip_runtime.h>
#include <math.h>

// MDTA v4: 5-kernel pipeline; k2 = reg/shfl stencil, k1 = 2-half GEMV.
// Shapes: B=4, DIM=64, H=W=256, HEADS=4, DHEAD=16, INNER=64, L=65536
#define NB 4
#define NC 64
#define NH 256
#define NW 256
#define NL (NH * NW)
#define NHEADS 4

typedef __attribute__((ext_vector_type(8))) short short8;
typedef __attribute__((ext_vector_type(8))) unsigned short ushort8;
typedef __attribute__((ext_vector_type(4))) float f32x4;

// ws layout: gram[4][4][288] floats at 0; Mt[4][64][64] floats at 8192 floats;
// qkv_pre bf16 at 1MB; qkvdw bf16 at 1MB+96MB.
#define GRAM_FLOATS 4608
#define MT_OFF_F 8192
#define QKV_PRE_OFF ((size_t)1 << 20)
#define QKV_BYTES ((size_t)192 * NL * NB * 2)
#define QKVDW_OFF (QKV_PRE_OFF + QKV_BYTES)
#define WS_NEEDED (QKVDW_OFF + QKV_BYTES)

__device__ __forceinline__ float bf2f(unsigned short u16) {
    union { unsigned int i; float f; } cv; cv.i = ((unsigned int)u16) << 16; return cv.f;
}
__device__ __forceinline__ unsigned short f2bf(float f) {
    union { float f; unsigned int i; } cv; cv.f = f;
    unsigned int x = cv.i;
    return (unsigned short)((x + 0x7FFFu + ((x >> 16) & 1u)) >> 16);   // RNE
}

// ===========================================================================
// K1: qkv = Wqkv[192,64] @ x[64,L], bf16 out. blockIdx.y = output half (96).
// Thread owns 1 pixel; xr[64] in regs; paired outputs for FMA ILP.
// ===========================================================================
__global__ __launch_bounds__(256) void k1_qkv(
    const float* __restrict__ x, const float* __restrict__ wqkv,
    unsigned short* __restrict__ qkv)
{
    const int b = blockIdx.z;
    const int half = blockIdx.y;
    const int p = blockIdx.x * 256 + threadIdx.x;
    const float* xp = x + (size_t)b * NC * NL + p;
    float xr[64];
    #pragma unroll
    for (int c = 0; c < 64; ++c) xr[c] = xp[(size_t)c * NL];

    unsigned short* outp = qkv + (size_t)b * 192 * NL + p;
    const int o0 = half * 96;
    for (int o = o0; o < o0 + 96; o += 2) {
        const float* w0 = wqkv + o * 64;        // uniform -> s_loads
        const float* w1 = w0 + 64;
        float a0 = 0.f, a1 = 0.f, b0 = 0.f, b1 = 0.f;
        #pragma unroll
        for (int c = 0; c < 64; c += 2) {
            a0 = fmaf(w0[c],     xr[c],     a0);
            a1 = fmaf(w0[c + 1], xr[c + 1], a1);
            b0 = fmaf(w1[c],     xr[c],     b0);
            b1 = fmaf(w1[c + 1], xr[c + 1], b1);
        }
        outp[(size_t)o * NL]       = f2bf(a0 + a1);
        outp[(size_t)(o + 1) * NL] = f2bf(b0 + b1);
    }
}

// ===========================================================================
// K2: depthwise 3x3 SAME, bf16->bf16, register/shfl stencil (no LDS).
// Thread owns 8 contiguous cols of one row. lane = rowpar*32 + cg.
// ===========================================================================
__global__ __launch_bounds__(256) void k2_dw(
    const unsigned short* __restrict__ qkv, const float* __restrict__ wdw,
    unsigned short* __restrict__ qkvdw)
{
    const int b = blockIdx.z, ch = blockIdx.y;
    const int r = blockIdx.x * 8 + (threadIdx.x >> 5);
    const int cg = threadIdx.x & 31;
    const int c0 = cg * 8;
    const unsigned short* in = qkv + ((size_t)b * 192 + ch) * NL;

    float w[9];
    #pragma unroll
    for (int i = 0; i < 9; ++i) w[i] = wdw[ch * 9 + i];   // uniform -> s_loads

    float v[3][8], lf[3], rt[3];
    #pragma unroll
    for (int dy = 0; dy < 3; ++dy) {
        const int rr = r + dy - 1;
        const bool valid = (rr >= 0) && (rr < NH);
        const int rc = valid ? rr : r;                     // safe clamped addr
        const ushort8 u = *(const ushort8*)(in + rc * NW + c0);
        #pragma unroll
        for (int i = 0; i < 8; ++i) v[dy][i] = valid ? bf2f(u[i]) : 0.f;
        // cross-thread edge pixels: cg-neighbors are lane-neighbors in-wave;
        // cg==0 / cg==31 edges are true image borders -> zero.
        lf[dy] = __shfl_up(v[dy][7], 1);
        rt[dy] = __shfl_down(v[dy][0], 1);
        if (cg == 0)  lf[dy] = 0.f;
        if (cg == 31) rt[dy] = 0.f;
    }

    float acc[8];
    #pragma unroll
    for (int i = 0; i < 8; ++i) {
        float a = 0.f;
        #pragma unroll
        for (int dy = 0; dy < 3; ++dy) {
            const float lv = (i == 0) ? lf[dy] : v[dy][i - 1];
            const float mv = v[dy][i];
            const float rv = (i == 7) ? rt[dy] : v[dy][i + 1];
            a = fmaf(w[dy * 3 + 0], lv, a);
            a = fmaf(w[dy * 3 + 1], mv, a);
            a = fmaf(w[dy * 3 + 2], rv, a);
        }
        acc[i] = a;
    }
    ushort8 o8;
    #pragma unroll
    for (int i = 0; i < 8; ++i) o8[i] = f2bf(acc[i]);
    *(ushort8*)(qkvdw + ((size_t)b * 192 + ch) * NL + r * NW + c0) = o8;
}

// ===========================================================================
// K3: per-head Gram via MFMA 16x16x32 bf16 + squared norms (layout verified).
// ===========================================================================
__global__ __launch_bounds__(256) void k3_gram(
    const unsigned short* __restrict__ qkvdw, float* __restrict__ gram)
{
    const int b = blockIdx.z, n = blockIdx.y;
    const int wave = threadIdx.x >> 6, lane = threadIdx.x & 63;
    const int p0 = blockIdx.x * 2048 + wave * 512;
    const unsigned short* qrow = qkvdw + ((size_t)b * 192 + n * 16 + (lane & 15)) * NL;
    const unsigned short* krow = qkvdw + ((size_t)b * 192 + 64 + n * 16 + (lane & 15)) * NL;
    const int koff = (lane >> 4) * 8;

    f32x4 acc = {0.f, 0.f, 0.f, 0.f};
    float qq = 0.f, kk = 0.f;
    for (int s = 0; s < 16; ++s) {
        const int p = p0 + s * 32 + koff;
        const short8 a  = *(const short8*)(qrow + p);
        const short8 bb = *(const short8*)(krow + p);
        acc = __builtin_amdgcn_mfma_f32_16x16x32_bf16(a, bb, acc, 0, 0, 0);
        #pragma unroll
        for (int j = 0; j < 8; ++j) {
            const float qv = bf2f((unsigned short)a[j]);
            const float kv = bf2f((unsigned short)bb[j]);
            qq = fmaf(qv, qv, qq);
            kk = fmaf(kv, kv, kk);
        }
    }
    float* gb = gram + (b * NHEADS + n) * 288;
    #pragma unroll
    for (int r = 0; r < 4; ++r)
        atomicAdd(gb + ((lane >> 4) * 4 + r) * 16 + (lane & 15), acc[r]);
    atomicAdd(gb + 256 + (lane & 15), qq);
    atomicAdd(gb + 272 + (lane & 15), kk);
}

// ===========================================================================
// K4: softmax(G/(|q||k|)*temp) over e, fold w_out into Mt[b][c][o].
// ===========================================================================
__global__ __launch_bounds__(256) void attn_kernel(
    const float* __restrict__ gram, const float* __restrict__ wout,
    const float* __restrict__ temp, float* __restrict__ Mt)
{
    __shared__ float attn_s[NHEADS][16][16];
    const int b = blockIdx.x;
    const int tid = threadIdx.x;

    if (tid < 64) {
        const int n = tid >> 4, d = tid & 15;
        const float* gb = gram + (b * NHEADS + n) * 288;
        const float nq = fmaxf(sqrtf(gb[256 + d]), 1e-12f);
        const float tn = temp[n];
        float lg[16];
        float mx = -3.4e38f;
        #pragma unroll
        for (int e = 0; e < 16; ++e) {
            const float nk = fmaxf(sqrtf(gb[272 + e]), 1e-12f);
            lg[e] = gb[d * 16 + e] / (nq * nk) * tn;
            mx = fmaxf(mx, lg[e]);
        }
        float s = 0.f;
        #pragma unroll
        for (int e = 0; e < 16; ++e) { lg[e] = expf(lg[e] - mx); s += lg[e]; }
        const float inv = 1.0f / s;
        #pragma unroll
        for (int e = 0; e < 16; ++e) attn_s[n][d][e] = lg[e] * inv;
    }
    __syncthreads();

    for (int idx = tid; idx < 4096; idx += 256) {
        const int c = idx >> 6;
        const int o = idx & 63;
        const int n = c >> 4, e = c & 15;
        float acc = 0.f;
        #pragma unroll
        for (int d = 0; d < 16; ++d)
            acc = fmaf(wout[o * 64 + n * 16 + d], attn_s[n][d][e], acc);
        Mt[b * 4096 + idx] = acc;
    }
}

// ===========================================================================
// K5: out[o][p] = sum_c Mt[c][o] * (vdw[c][p] * illu[c][p]).
// ===========================================================================
__global__ __launch_bounds__(256) void k5_out(
    const unsigned short* __restrict__ qkvdw, const float* __restrict__ illu,
    const float* __restrict__ Mt, float* __restrict__ out)
{
    const int b = blockIdx.y;
    const int p = blockIdx.x * 256 + threadIdx.x;
    const unsigned short* vp = qkvdw + ((size_t)b * 192 + 128) * NL + p;
    const float* ip = illu + (size_t)b * 64 * NL + p;
    const float* mb = Mt + b * 4096;

    float y[64];
    #pragma unroll
    for (int o = 0; o < 64; ++o) y[o] = 0.f;

    #pragma unroll 4
    for (int c = 0; c < 64; ++c) {
        const float vi = bf2f(vp[(size_t)c * NL]) * ip[(size_t)c * NL];
        const float* m = mb + c * 64;   // uniform -> s_loads
        #pragma unroll
        for (int o = 0; o < 64; ++o) y[o] = fmaf(m[o], vi, y[o]);
    }

    float* op = out + (size_t)b * 64 * NL + p;
    #pragma unroll
    for (int o = 0; o < 64; ++o) op[(size_t)o * NL] = y[o];
}

// ===========================================================================
// FALLBACK (round-2 proven path, used only if ws_size < WS_NEEDED)
// ===========================================================================
__global__ __launch_bounds__(256, 2) void fb_pass1(
    const float* __restrict__ x, const float* __restrict__ wqkv,
    const float* __restrict__ wdw, float* __restrict__ gram)
{
    __shared__ float predw[32][328];
    __shared__ float qk[32][262];
    const int bid = blockIdx.x;
    const int b = bid >> 8;
    const int tile = bid & 255;
    const int y0 = (tile >> 4) << 4;
    const int x0 = (tile & 15) << 4;
    const int tid = threadIdx.x;
    const int iy = tid >> 4, ix = tid & 15;

    for (int n = 0; n < NHEADS; ++n) {
        for (int task = tid; task < 324; task += 256) {
            const int hy = task / 18;
            const int hx = task - hy * 18;
            const int py = y0 + hy - 1;
            const int px = x0 + hx - 1;
            const bool valid = (py >= 0) && (py < NH) && (px >= 0) && (px < NW);
            const float* xp = x + (size_t)b * (NC * NL) + py * NW + px;
            float xr[NC];
            #pragma unroll
            for (int c = 0; c < NC; ++c)
                xr[c] = valid ? xp[(size_t)c * NL] : 0.0f;
            for (int j = 0; j < 16; ++j) {
                const float* wq = wqkv + (n * 16 + j) * NC;
                const float* wk = wqkv + (64 + n * 16 + j) * NC;
                float aq = 0.f, ak = 0.f;
                #pragma unroll
                for (int c = 0; c < NC; ++c) {
                    aq = fmaf(wq[c], xr[c], aq);
                    ak = fmaf(wk[c], xr[c], ak);
                }
                predw[j][task] = aq;
                predw[16 + j][task] = ak;
            }
        }
        __syncthreads();
        {
            const int hp = (iy + 1) * 18 + (ix + 1);
            #pragma unroll
            for (int j = 0; j < 32; ++j) {
                const int ch = (j < 16) ? (n * 16 + j) : (64 + n * 16 + (j - 16));
                const float* wd = wdw + ch * 9;
                float a = 0.f;
                #pragma unroll
                for (int t9 = 0; t9 < 9; ++t9) {
                    const int dy = t9 / 3, dx = t9 - dy * 3;
                    a = fmaf(wd[t9], predw[j][hp + (dy - 1) * 18 + (dx - 1)], a);
                }
                qk[j][tid] = a;
            }
        }
        __syncthreads();
        {
            const int d = tid >> 4, e = tid & 15;
            float acc = 0.f;
            #pragma unroll 8
            for (int p = 0; p < 256; ++p)
                acc = fmaf(qk[d][p], qk[16 + e][p], acc);
            float* gb = gram + ((b * NHEADS + n) * 288);
            atomicAdd(gb + tid, acc);
            if (tid < 32) {
                float s = 0.f;
                #pragma unroll 8
                for (int p = 0; p < 256; ++p) {
                    const float v = qk[tid][p];
                    s = fmaf(v, v, s);
                }
                atomicAdd(gb + 256 + tid, s);
            }
        }
        __syncthreads();
    }
}

__global__ __launch_bounds__(256, 2) void fb_pass2(
    const float* __restrict__ x, const float* __restrict__ illu,
    const float* __restrict__ wqkv, const float* __restrict__ wdw,
    const float* __restrict__ Mt, float* __restrict__ out)
{
    __shared__ float predw[32][328];
    const int bid = blockIdx.x;
    const int b = bid >> 8;
    const int tile = bid & 255;
    const int y0 = (tile >> 4) << 4;
    const int x0 = (tile & 15) << 4;
    const int tid = threadIdx.x;
    const int iy = tid >> 4, ix = tid & 15;
    const int pidx = (y0 + iy) * NW + (x0 + ix);

    float y[64];
    #pragma unroll
    for (int o = 0; o < 64; ++o) y[o] = 0.f;

    for (int cv = 0; cv < 2; ++cv) {
        if (cv) __syncthreads();
        for (int half = 0; half < 2; ++half) {
            for (int task = tid; task < 324; task += 256) {
                const int hy = task / 18;
                const int hx = task - hy * 18;
                const int py = y0 + hy - 1;
                const int px = x0 + hx - 1;
                const bool valid = (py >= 0) && (py < NH) && (px >= 0) && (px < NW);
                const float* xp = x + (size_t)b * (NC * NL) + py * NW + px
                                  + (size_t)(half * 32) * NL;
                float xr[32];
                #pragma unroll
                for (int c = 0; c < 32; ++c)
                    xr[c] = valid ? xp[(size_t)c * NL] : 0.0f;
                for (int j = 0; j < 32; ++j) {
                    const float* wv = wqkv + (128 + cv * 32 + j) * NC + half * 32;
                    float a = 0.f;
                    #pragma unroll
                    for (int c = 0; c < 32; ++c) a = fmaf(wv[c], xr[c], a);
                    if (half == 0) predw[j][task] = a;
                    else           predw[j][task] += a;
                }
            }
        }
        __syncthreads();
        {
            const int hp = (iy + 1) * 18 + (ix + 1);
            for (int j = 0; j < 32; ++j) {
                const int ci = cv * 32 + j;
                const float* wd = wdw + (128 + ci) * 9;
                float a = 0.f;
                #pragma unroll
                for (int t9 = 0; t9 < 9; ++t9) {
                    const int dy = t9 / 3, dx = t9 - dy * 3;
                    a = fmaf(wd[t9], predw[j][hp + (dy - 1) * 18 + (dx - 1)], a);
                }
                const float vi = a * illu[(size_t)(b * 64 + ci) * NL + pidx];
                const float* mrow = Mt + b * 4096 + ci * 64;
                #pragma unroll
                for (int o = 0; o < 64; ++o)
                    y[o] = fmaf(mrow[o], vi, y[o]);
            }
        }
    }
    const size_t obase = (size_t)b * (64 * NL) + pidx;
    #pragma unroll
    for (int o = 0; o < 64; ++o)
        out[obase + (size_t)o * NL] = y[o];
}

// ===========================================================================
extern "C" void kernel_launch(void* const* d_in, const int* in_sizes, int n_in,
                              void* d_out, int out_size, void* d_ws, size_t ws_size,
                              hipStream_t stream)
{
    const float* x    = (const float*)d_in[0];
    const float* illu = (const float*)d_in[1];
    const float* wqkv = (const float*)d_in[2];
    const float* wdw  = (const float*)d_in[3];
    const float* wout = (const float*)d_in[4];
    const float* temp = (const float*)d_in[5];
    float* out = (float*)d_out;
    float* ws  = (float*)d_ws;

    float* gram = ws;                 // 4608 floats
    float* Mt   = ws + MT_OFF_F;      // 16384 floats

    hipMemsetAsync(gram, 0, GRAM_FLOATS * sizeof(float), stream);

    if (ws_size >= WS_NEEDED) {
        unsigned short* qkv_pre = (unsigned short*)((char*)d_ws + QKV_PRE_OFF);
        unsigned short* qkvdw   = (unsigned short*)((char*)d_ws + QKVDW_OFF);

        k1_qkv <<<dim3(NL / 256, 2, NB), dim3(256), 0, stream>>>(x, wqkv, qkv_pre);
        k2_dw  <<<dim3(NH / 8, 192, NB), dim3(256), 0, stream>>>(qkv_pre, wdw, qkvdw);
        k3_gram<<<dim3(32, NHEADS, NB),  dim3(256), 0, stream>>>(qkvdw, gram);
        attn_kernel<<<dim3(NB), dim3(256), 0, stream>>>(gram, wout, temp, Mt);
        k5_out <<<dim3(NL / 256, NB),    dim3(256), 0, stream>>>(qkvdw, illu, Mt, out);
    } else {
        fb_pass1<<<dim3(1024), dim3(256), 0, stream>>>(x, wqkv, wdw, gram);
        attn_kernel<<<dim3(NB), dim3(256), 0, stream>>>(gram, wout, temp, Mt);
        fb_pass2<<<dim3(1024), dim3(256), 0, stream>>>(x, illu, wqkv, wdw, Mt, out);
    }
}

// Round 6
// 357.987 us; speedup vs baseline: 1.6832x; 1.6832x over previous
//
#include <hip/hip_runtime.h>
#include <math.h>

// MDTA v5: k1 -> MFMA bf16 GEMM (layout proven in k3); k2 reg/shfl stencil.
// Shapes: B=4, DIM=64, H=W=256, HEADS=4, DHEAD=16, INNER=64, L=65536
#define NB 4
#define NC 64
#define NH 256
#define NW 256
#define NL (NH * NW)
#define NHEADS 4

typedef __attribute__((ext_vector_type(8))) short short8;
typedef __attribute__((ext_vector_type(8))) unsigned short ushort8;
typedef __attribute__((ext_vector_type(4))) float f32x4;

// ws layout: gram[4][4][288] floats at 0; Mt[4][64][64] floats at 8192 floats;
// qkv_pre bf16 at 1MB; qkvdw bf16 at 1MB+96MB.
#define GRAM_FLOATS 4608
#define MT_OFF_F 8192
#define QKV_PRE_OFF ((size_t)1 << 20)
#define QKV_BYTES ((size_t)192 * NL * NB * 2)
#define QKVDW_OFF (QKV_PRE_OFF + QKV_BYTES)
#define WS_NEEDED (QKVDW_OFF + QKV_BYTES)

__device__ __forceinline__ float bf2f(unsigned short u16) {
    union { unsigned int i; float f; } cv; cv.i = ((unsigned int)u16) << 16; return cv.f;
}
__device__ __forceinline__ unsigned short f2bf(float f) {
    union { float f; unsigned int i; } cv; cv.f = f;
    unsigned int x = cv.i;
    return (unsigned short)((x + 0x7FFFu + ((x >> 16) & 1u)) >> 16);   // RNE
}

// ===========================================================================
// K1: qkv = Wqkv[192,64] @ x[64,L] via MFMA 16x16x32 bf16.
// Wave owns 16 out-channels (A-frag = W rows, loaded once). Per 16-px tile:
// B-frag = x channels (strided f32 -> bf16), 2 chained MFMAs (K=64), store
// D as bf16. D layout (k3-verified): row(out)=(lane>>4)*4+r, col(px)=lane&15.
// blockIdx.y = out-group of 64 (3 groups) so x is logically read 3x (L3-hot).
// ===========================================================================
__global__ __launch_bounds__(256) void k1_qkv_mfma(
    const float* __restrict__ x, const float* __restrict__ wqkv,
    unsigned short* __restrict__ qkv)
{
    const int b = blockIdx.z;
    const int og = blockIdx.y;                 // 0..2: out-group of 64
    const int wave = threadIdx.x >> 6;
    const int lane = threadIdx.x & 63;
    const int ln  = lane & 15;
    const int kb  = (lane >> 4) * 8;           // k-offset within 32-chunk
    const int oc0 = og * 64 + wave * 16;       // this wave's 16 out-channels
    const int px0 = blockIdx.x * 256;

    // A-frags: 16 W rows, k-halves 0..31 / 32..63, bf16
    short8 wf0, wf1;
    {
        const float* wrow = wqkv + (oc0 + ln) * 64;
        #pragma unroll
        for (int j = 0; j < 8; ++j) {
            wf0[j] = (short)f2bf(wrow[kb + j]);
            wf1[j] = (short)f2bf(wrow[32 + kb + j]);
        }
    }

    const float* xb = x + (size_t)b * NC * NL;
    unsigned short* outp = qkv + (size_t)b * 192 * NL;

    #pragma unroll 2
    for (int it = 0; it < 16; ++it) {
        const int p = px0 + it * 16 + ln;
        short8 xf0, xf1;
        #pragma unroll
        for (int j = 0; j < 8; ++j) {
            xf0[j] = (short)f2bf(xb[(size_t)(kb + j) * NL + p]);
            xf1[j] = (short)f2bf(xb[(size_t)(32 + kb + j) * NL + p]);
        }
        f32x4 acc = {0.f, 0.f, 0.f, 0.f};
        acc = __builtin_amdgcn_mfma_f32_16x16x32_bf16(wf0, xf0, acc, 0, 0, 0);
        acc = __builtin_amdgcn_mfma_f32_16x16x32_bf16(wf1, xf1, acc, 0, 0, 0);
        const int prow = (lane >> 4) * 4;
        #pragma unroll
        for (int r = 0; r < 4; ++r)
            outp[(size_t)(oc0 + prow + r) * NL + p] = f2bf(acc[r]);
    }
}

// ===========================================================================
// K2: depthwise 3x3 SAME, bf16->bf16, register/shfl stencil (no LDS).
// Thread owns 8 contiguous cols of one row. lane = rowpar*32 + cg.
// ===========================================================================
__global__ __launch_bounds__(256) void k2_dw(
    const unsigned short* __restrict__ qkv, const float* __restrict__ wdw,
    unsigned short* __restrict__ qkvdw)
{
    const int b = blockIdx.z, ch = blockIdx.y;
    const int r = blockIdx.x * 8 + (threadIdx.x >> 5);
    const int cg = threadIdx.x & 31;
    const int c0 = cg * 8;
    const unsigned short* in = qkv + ((size_t)b * 192 + ch) * NL;

    float w[9];
    #pragma unroll
    for (int i = 0; i < 9; ++i) w[i] = wdw[ch * 9 + i];   // uniform -> s_loads

    float v[3][8], lf[3], rt[3];
    #pragma unroll
    for (int dy = 0; dy < 3; ++dy) {
        const int rr = r + dy - 1;
        const bool valid = (rr >= 0) && (rr < NH);
        const int rc = valid ? rr : r;                     // safe clamped addr
        const ushort8 u = *(const ushort8*)(in + rc * NW + c0);
        #pragma unroll
        for (int i = 0; i < 8; ++i) v[dy][i] = valid ? bf2f(u[i]) : 0.f;
        lf[dy] = __shfl_up(v[dy][7], 1);
        rt[dy] = __shfl_down(v[dy][0], 1);
        if (cg == 0)  lf[dy] = 0.f;
        if (cg == 31) rt[dy] = 0.f;
    }

    float acc[8];
    #pragma unroll
    for (int i = 0; i < 8; ++i) {
        float a = 0.f;
        #pragma unroll
        for (int dy = 0; dy < 3; ++dy) {
            const float lv = (i == 0) ? lf[dy] : v[dy][i - 1];
            const float mv = v[dy][i];
            const float rv = (i == 7) ? rt[dy] : v[dy][i + 1];
            a = fmaf(w[dy * 3 + 0], lv, a);
            a = fmaf(w[dy * 3 + 1], mv, a);
            a = fmaf(w[dy * 3 + 2], rv, a);
        }
        acc[i] = a;
    }
    ushort8 o8;
    #pragma unroll
    for (int i = 0; i < 8; ++i) o8[i] = f2bf(acc[i]);
    *(ushort8*)(qkvdw + ((size_t)b * 192 + ch) * NL + r * NW + c0) = o8;
}

// ===========================================================================
// K3: per-head Gram via MFMA 16x16x32 bf16 + squared norms (layout verified).
// ===========================================================================
__global__ __launch_bounds__(256) void k3_gram(
    const unsigned short* __restrict__ qkvdw, float* __restrict__ gram)
{
    const int b = blockIdx.z, n = blockIdx.y;
    const int wave = threadIdx.x >> 6, lane = threadIdx.x & 63;
    const int p0 = blockIdx.x * 2048 + wave * 512;
    const unsigned short* qrow = qkvdw + ((size_t)b * 192 + n * 16 + (lane & 15)) * NL;
    const unsigned short* krow = qkvdw + ((size_t)b * 192 + 64 + n * 16 + (lane & 15)) * NL;
    const int koff = (lane >> 4) * 8;

    f32x4 acc = {0.f, 0.f, 0.f, 0.f};
    float qq = 0.f, kk = 0.f;
    for (int s = 0; s < 16; ++s) {
        const int p = p0 + s * 32 + koff;
        const short8 a  = *(const short8*)(qrow + p);
        const short8 bb = *(const short8*)(krow + p);
        acc = __builtin_amdgcn_mfma_f32_16x16x32_bf16(a, bb, acc, 0, 0, 0);
        #pragma unroll
        for (int j = 0; j < 8; ++j) {
            const float qv = bf2f((unsigned short)a[j]);
            const float kv = bf2f((unsigned short)bb[j]);
            qq = fmaf(qv, qv, qq);
            kk = fmaf(kv, kv, kk);
        }
    }
    float* gb = gram + (b * NHEADS + n) * 288;
    #pragma unroll
    for (int r = 0; r < 4; ++r)
        atomicAdd(gb + ((lane >> 4) * 4 + r) * 16 + (lane & 15), acc[r]);
    atomicAdd(gb + 256 + (lane & 15), qq);
    atomicAdd(gb + 272 + (lane & 15), kk);
}

// ===========================================================================
// K4: softmax(G/(|q||k|)*temp) over e, fold w_out into Mt[b][c][o].
// ===========================================================================
__global__ __launch_bounds__(256) void attn_kernel(
    const float* __restrict__ gram, const float* __restrict__ wout,
    const float* __restrict__ temp, float* __restrict__ Mt)
{
    __shared__ float attn_s[NHEADS][16][16];
    const int b = blockIdx.x;
    const int tid = threadIdx.x;

    if (tid < 64) {
        const int n = tid >> 4, d = tid & 15;
        const float* gb = gram + (b * NHEADS + n) * 288;
        const float nq = fmaxf(sqrtf(gb[256 + d]), 1e-12f);
        const float tn = temp[n];
        float lg[16];
        float mx = -3.4e38f;
        #pragma unroll
        for (int e = 0; e < 16; ++e) {
            const float nk = fmaxf(sqrtf(gb[272 + e]), 1e-12f);
            lg[e] = gb[d * 16 + e] / (nq * nk) * tn;
            mx = fmaxf(mx, lg[e]);
        }
        float s = 0.f;
        #pragma unroll
        for (int e = 0; e < 16; ++e) { lg[e] = expf(lg[e] - mx); s += lg[e]; }
        const float inv = 1.0f / s;
        #pragma unroll
        for (int e = 0; e < 16; ++e) attn_s[n][d][e] = lg[e] * inv;
    }
    __syncthreads();

    for (int idx = tid; idx < 4096; idx += 256) {
        const int c = idx >> 6;
        const int o = idx & 63;
        const int n = c >> 4, e = c & 15;
        float acc = 0.f;
        #pragma unroll
        for (int d = 0; d < 16; ++d)
            acc = fmaf(wout[o * 64 + n * 16 + d], attn_s[n][d][e], acc);
        Mt[b * 4096 + idx] = acc;
    }
}

// ===========================================================================
// K5: out[o][p] = sum_c Mt[c][o] * (vdw[c][p] * illu[c][p]).
// ===========================================================================
__global__ __launch_bounds__(256) void k5_out(
    const unsigned short* __restrict__ qkvdw, const float* __restrict__ illu,
    const float* __restrict__ Mt, float* __restrict__ out)
{
    const int b = blockIdx.y;
    const int p = blockIdx.x * 256 + threadIdx.x;
    const unsigned short* vp = qkvdw + ((size_t)b * 192 + 128) * NL + p;
    const float* ip = illu + (size_t)b * 64 * NL + p;
    const float* mb = Mt + b * 4096;

    float y[64];
    #pragma unroll
    for (int o = 0; o < 64; ++o) y[o] = 0.f;

    #pragma unroll 4
    for (int c = 0; c < 64; ++c) {
        const float vi = bf2f(vp[(size_t)c * NL]) * ip[(size_t)c * NL];
        const float* m = mb + c * 64;   // uniform -> s_loads
        #pragma unroll
        for (int o = 0; o < 64; ++o) y[o] = fmaf(m[o], vi, y[o]);
    }

    float* op = out + (size_t)b * 64 * NL + p;
    #pragma unroll
    for (int o = 0; o < 64; ++o) op[(size_t)o * NL] = y[o];
}

// ===========================================================================
// FALLBACK (round-2 proven path, used only if ws_size < WS_NEEDED)
// ===========================================================================
__global__ __launch_bounds__(256, 2) void fb_pass1(
    const float* __restrict__ x, const float* __restrict__ wqkv,
    const float* __restrict__ wdw, float* __restrict__ gram)
{
    __shared__ float predw[32][328];
    __shared__ float qk[32][262];
    const int bid = blockIdx.x;
    const int b = bid >> 8;
    const int tile = bid & 255;
    const int y0 = (tile >> 4) << 4;
    const int x0 = (tile & 15) << 4;
    const int tid = threadIdx.x;
    const int iy = tid >> 4, ix = tid & 15;

    for (int n = 0; n < NHEADS; ++n) {
        for (int task = tid; task < 324; task += 256) {
            const int hy = task / 18;
            const int hx = task - hy * 18;
            const int py = y0 + hy - 1;
            const int px = x0 + hx - 1;
            const bool valid = (py >= 0) && (py < NH) && (px >= 0) && (px < NW);
            const float* xp = x + (size_t)b * (NC * NL) + py * NW + px;
            float xr[NC];
            #pragma unroll
            for (int c = 0; c < NC; ++c)
                xr[c] = valid ? xp[(size_t)c * NL] : 0.0f;
            for (int j = 0; j < 16; ++j) {
                const float* wq = wqkv + (n * 16 + j) * NC;
                const float* wk = wqkv + (64 + n * 16 + j) * NC;
                float aq = 0.f, ak = 0.f;
                #pragma unroll
                for (int c = 0; c < NC; ++c) {
                    aq = fmaf(wq[c], xr[c], aq);
                    ak = fmaf(wk[c], xr[c], ak);
                }
                predw[j][task] = aq;
                predw[16 + j][task] = ak;
            }
        }
        __syncthreads();
        {
            const int hp = (iy + 1) * 18 + (ix + 1);
            #pragma unroll
            for (int j = 0; j < 32; ++j) {
                const int ch = (j < 16) ? (n * 16 + j) : (64 + n * 16 + (j - 16));
                const float* wd = wdw + ch * 9;
                float a = 0.f;
                #pragma unroll
                for (int t9 = 0; t9 < 9; ++t9) {
                    const int dy = t9 / 3, dx = t9 - dy * 3;
                    a = fmaf(wd[t9], predw[j][hp + (dy - 1) * 18 + (dx - 1)], a);
                }
                qk[j][tid] = a;
            }
        }
        __syncthreads();
        {
            const int d = tid >> 4, e = tid & 15;
            float acc = 0.f;
            #pragma unroll 8
            for (int p = 0; p < 256; ++p)
                acc = fmaf(qk[d][p], qk[16 + e][p], acc);
            float* gb = gram + ((b * NHEADS + n) * 288);
            atomicAdd(gb + tid, acc);
            if (tid < 32) {
                float s = 0.f;
                #pragma unroll 8
                for (int p = 0; p < 256; ++p) {
                    const float v = qk[tid][p];
                    s = fmaf(v, v, s);
                }
                atomicAdd(gb + 256 + tid, s);
            }
        }
        __syncthreads();
    }
}

__global__ __launch_bounds__(256, 2) void fb_pass2(
    const float* __restrict__ x, const float* __restrict__ illu,
    const float* __restrict__ wqkv, const float* __restrict__ wdw,
    const float* __restrict__ Mt, float* __restrict__ out)
{
    __shared__ float predw[32][328];
    const int bid = blockIdx.x;
    const int b = bid >> 8;
    const int tile = bid & 255;
    const int y0 = (tile >> 4) << 4;
    const int x0 = (tile & 15) << 4;
    const int tid = threadIdx.x;
    const int iy = tid >> 4, ix = tid & 15;
    const int pidx = (y0 + iy) * NW + (x0 + ix);

    float y[64];
    #pragma unroll
    for (int o = 0; o < 64; ++o) y[o] = 0.f;

    for (int cv = 0; cv < 2; ++cv) {
        if (cv) __syncthreads();
        for (int half = 0; half < 2; ++half) {
            for (int task = tid; task < 324; task += 256) {
                const int hy = task / 18;
                const int hx = task - hy * 18;
                const int py = y0 + hy - 1;
                const int px = x0 + hx - 1;
                const bool valid = (py >= 0) && (py < NH) && (px >= 0) && (px < NW);
                const float* xp = x + (size_t)b * (NC * NL) + py * NW + px
                                  + (size_t)(half * 32) * NL;
                float xr[32];
                #pragma unroll
                for (int c = 0; c < 32; ++c)
                    xr[c] = valid ? xp[(size_t)c * NL] : 0.0f;
                for (int j = 0; j < 32; ++j) {
                    const float* wv = wqkv + (128 + cv * 32 + j) * NC + half * 32;
                    float a = 0.f;
                    #pragma unroll
                    for (int c = 0; c < 32; ++c) a = fmaf(wv[c], xr[c], a);
                    if (half == 0) predw[j][task] = a;
                    else           predw[j][task] += a;
                }
            }
        }
        __syncthreads();
        {
            const int hp = (iy + 1) * 18 + (ix + 1);
            for (int j = 0; j < 32; ++j) {
                const int ci = cv * 32 + j;
                const float* wd = wdw + (128 + ci) * 9;
                float a = 0.f;
                #pragma unroll
                for (int t9 = 0; t9 < 9; ++t9) {
                    const int dy = t9 / 3, dx = t9 - dy * 3;
                    a = fmaf(wd[t9], predw[j][hp + (dy - 1) * 18 + (dx - 1)], a);
                }
                const float vi = a * illu[(size_t)(b * 64 + ci) * NL + pidx];
                const float* mrow = Mt + b * 4096 + ci * 64;
                #pragma unroll
                for (int o = 0; o < 64; ++o)
                    y[o] = fmaf(mrow[o], vi, y[o]);
            }
        }
    }
    const size_t obase = (size_t)b * (64 * NL) + pidx;
    #pragma unroll
    for (int o = 0; o < 64; ++o)
        out[obase + (size_t)o * NL] = y[o];
}

// ===========================================================================
extern "C" void kernel_launch(void* const* d_in, const int* in_sizes, int n_in,
                              void* d_out, int out_size, void* d_ws, size_t ws_size,
                              hipStream_t stream)
{
    const float* x    = (const float*)d_in[0];
    const float* illu = (const float*)d_in[1];
    const float* wqkv = (const float*)d_in[2];
    const float* wdw  = (const float*)d_in[3];
    const float* wout = (const float*)d_in[4];
    const float* temp = (const float*)d_in[5];
    float* out = (float*)d_out;
    float* ws  = (float*)d_ws;

    float* gram = ws;                 // 4608 floats
    float* Mt   = ws + MT_OFF_F;      // 16384 floats

    hipMemsetAsync(gram, 0, GRAM_FLOATS * sizeof(float), stream);

    if (ws_size >= WS_NEEDED) {
        unsigned short* qkv_pre = (unsigned short*)((char*)d_ws + QKV_PRE_OFF);
        unsigned short* qkvdw   = (unsigned short*)((char*)d_ws + QKVDW_OFF);

        k1_qkv_mfma<<<dim3(NL / 256, 3, NB), dim3(256), 0, stream>>>(x, wqkv, qkv_pre);
        k2_dw  <<<dim3(NH / 8, 192, NB), dim3(256), 0, stream>>>(qkv_pre, wdw, qkvdw);
        k3_gram<<<dim3(32, NHEADS, NB),  dim3(256), 0, stream>>>(qkvdw, gram);
        attn_kernel<<<dim3(NB), dim3(256), 0, stream>>>(gram, wout, temp, Mt);
        k5_out <<<dim3(NL / 256, NB),    dim3(256), 0, stream>>>(qkvdw, illu, Mt, out);
    } else {
        fb_pass1<<<dim3(1024), dim3(256), 0, stream>>>(x, wqkv, wdw, gram);
        attn_kernel<<<dim3(NB), dim3(256), 0, stream>>>(gram, wout, temp, Mt);
        fb_pass2<<<dim3(1024), dim3(256), 0, stream>>>(x, illu, wqkv, wdw, Mt, out);
    }
}